// Round 1
// baseline (4564.057 us; speedup 1.0000x reference)
//
#include <hip/hip_runtime.h>

#define N_U 100000
#define N_B 20000
#define E_UB 3200000
#define E_UU 1600000
#define E_BB 320000
#define IN_DIM 384
#define D 128

// ---------------- CSR build ----------------

__global__ void count_kernel(const int* __restrict__ dst, int n, int* __restrict__ cnt) {
    int i = blockIdx.x * blockDim.x + threadIdx.x;
    int stride = gridDim.x * blockDim.x;
    for (; i < n; i += stride) atomicAdd(&cnt[dst[i]], 1);
}

// Single-block exclusive scan over cnt[0..n) -> rowptr[0..n], cursor[i]=rowptr[i].
// cursor may alias cnt (read cnt[i] into a temp before overwriting).
__global__ void scan_kernel(int* __restrict__ cnt, int n,
                            int* __restrict__ rowptr, int* __restrict__ cursor) {
    __shared__ int sh[1024];
    int t = threadIdx.x;
    int seg = (n + 1023) >> 10;
    int lo = t * seg;
    int hi = min(n, lo + seg);
    int s = 0;
    for (int i = lo; i < hi; ++i) s += cnt[i];
    sh[t] = s;
    __syncthreads();
    for (int off = 1; off < 1024; off <<= 1) {
        int add = 0;
        if (t >= off) add = sh[t - off];
        __syncthreads();
        sh[t] += add;
        __syncthreads();
    }
    int run = sh[t] - s;  // exclusive prefix for this thread's segment
    for (int i = lo; i < hi; ++i) {
        int c = cnt[i];
        rowptr[i] = run;
        cursor[i] = run;   // may alias cnt[i]; c already read
        run += c;
    }
    if (t == 1023) rowptr[n] = sh[1023];
}

__global__ void fill_kernel(const int* __restrict__ src, const int* __restrict__ dst,
                            const float* __restrict__ val, int n,
                            int* __restrict__ cursor, int* __restrict__ col,
                            float* __restrict__ vals) {
    int i = blockIdx.x * blockDim.x + threadIdx.x;
    int stride = gridDim.x * blockDim.x;
    for (; i < n; i += stride) {
        int d = dst[i];
        int idx = atomicAdd(&cursor[d], 1);
        col[idx] = src[i];
        vals[idx] = val[i];
    }
}

// ---------------- dense GEMM: out = X[n,384] @ W[384,128], writes cur and sum ----------------

__global__ void gemm_kernel(const float* __restrict__ X, const float* __restrict__ W, int n,
                            float* __restrict__ cur, float* __restrict__ sum) {
    __shared__ float sx[8 * IN_DIM];
    int base = blockIdx.x * 8;
    for (int i = threadIdx.x; i < 8 * IN_DIM; i += 256) {
        int r = base + i / IN_DIM;
        sx[i] = (r < n) ? X[(size_t)r * IN_DIM + (i % IN_DIM)] : 0.f;
    }
    __syncthreads();
    int col = threadIdx.x & 127;
    int rh  = threadIdx.x >> 7;  // 0 or 1
    float acc[4] = {0.f, 0.f, 0.f, 0.f};
    for (int k = 0; k < IN_DIM; ++k) {
        float wv = W[k * D + col];
#pragma unroll
        for (int j = 0; j < 4; ++j)
            acc[j] += sx[(rh * 4 + j) * IN_DIM + k] * wv;
    }
#pragma unroll
    for (int j = 0; j < 4; ++j) {
        int r = base + rh * 4 + j;
        if (r < n) {
            size_t o = (size_t)r * D + col;
            cur[o] = acc[j];
            sum[o] = acc[j];
        }
    }
}

// ---------------- pull SpMM: one wave per dst row, float2 per lane ----------------

__global__ void spmm_first(const int* __restrict__ rowptr, const int* __restrict__ col,
                           const float* __restrict__ vals, const float* __restrict__ x,
                           float* __restrict__ y, int n) {
    int wave = threadIdx.x >> 6;
    int lane = threadIdx.x & 63;
    int r = blockIdx.x * 4 + wave;
    if (r >= n) return;
    int s = rowptr[r], e = rowptr[r + 1];
    const float2* x2 = (const float2*)x;
    float2 acc = {0.f, 0.f};
    for (int i = s; i < e; ++i) {
        int c = col[i];
        float w = vals[i];
        float2 xv = x2[(size_t)c * 64 + lane];
        acc.x += w * xv.x;
        acc.y += w * xv.y;
    }
    ((float2*)y)[(size_t)r * 64 + lane] = acc;
}

__global__ void spmm_second(const int* __restrict__ rowptr, const int* __restrict__ col,
                            const float* __restrict__ vals, const float* __restrict__ x,
                            float* __restrict__ y, float* __restrict__ sum, int n) {
    int wave = threadIdx.x >> 6;
    int lane = threadIdx.x & 63;
    int r = blockIdx.x * 4 + wave;
    if (r >= n) return;
    int s = rowptr[r], e = rowptr[r + 1];
    const float2* x2 = (const float2*)x;
    float2 acc = {0.f, 0.f};
    for (int i = s; i < e; ++i) {
        int c = col[i];
        float w = vals[i];
        float2 xv = x2[(size_t)c * 64 + lane];
        acc.x += w * xv.x;
        acc.y += w * xv.y;
    }
    size_t o = (size_t)r * 64 + lane;
    float2 prev = ((float2*)y)[o];
    float2 t = {prev.x + acc.x, prev.y + acc.y};
    ((float2*)y)[o] = t;
    float2 sv = ((float2*)sum)[o];
    sv.x += t.x;
    sv.y += t.y;
    ((float2*)sum)[o] = sv;
}

// ---------------- normalize: x = (sum*0.25); x / max(||x||,1e-12), in place ----------------

__global__ void norm_kernel(float* __restrict__ out, int n) {
    int wave = threadIdx.x >> 6;
    int lane = threadIdx.x & 63;
    int r = blockIdx.x * 4 + wave;
    if (r >= n) return;
    float2* p = (float2*)out + (size_t)r * 64 + lane;
    float2 v = *p;
    v.x *= 0.25f;
    v.y *= 0.25f;
    float ss = v.x * v.x + v.y * v.y;
    for (int off = 32; off > 0; off >>= 1) ss += __shfl_down(ss, off);
    ss = __shfl(ss, 0);
    float inv = 1.f / fmaxf(sqrtf(ss), 1e-12f);
    v.x *= inv;
    v.y *= inv;
    *p = v;
}

// ---------------- launch ----------------

extern "C" void kernel_launch(void* const* d_in, const int* in_sizes, int n_in,
                              void* d_out, int out_size, void* d_ws, size_t ws_size,
                              hipStream_t stream) {
    const float* user_feat = (const float*)d_in[0];
    const float* biz_feat  = (const float*)d_in[1];
    const float* W_user    = (const float*)d_in[2];
    const float* W_biz     = (const float*)d_in[3];
    const int*   ub_u      = (const int*)d_in[4];
    const int*   ub_b      = (const int*)d_in[5];
    const float* val_ub    = (const float*)d_in[6];
    const float* val_bu    = (const float*)d_in[7];
    const int*   uu_src    = (const int*)d_in[8];
    const int*   uu_dst    = (const int*)d_in[9];
    const float* uu_val    = (const float*)d_in[10];
    const int*   bb_src    = (const int*)d_in[11];
    const int*   bb_dst    = (const int*)d_in[12];
    const float* bb_val    = (const float*)d_in[13];

    float* out   = (float*)d_out;
    float* u_sum = out;                      // [N_U, D]
    float* b_sum = out + (size_t)N_U * D;    // [N_B, D]

    char* ws = (char*)d_ws;
    size_t off = 0;
    auto alloc = [&](size_t elems) -> void* {
        void* p = ws + off;
        off += ((elems * 4 + 255) / 256) * 256;
        return p;
    };
    float* u_cur = (float*)alloc((size_t)N_U * D);
    float* u_nxt = (float*)alloc((size_t)N_U * D);
    float* b_cur = (float*)alloc((size_t)N_B * D);
    float* b_nxt = (float*)alloc((size_t)N_B * D);
    int*   col_bu = (int*)alloc(E_UB);  float* w_bu = (float*)alloc(E_UB);
    int*   col_uu = (int*)alloc(E_UU);  float* w_uu = (float*)alloc(E_UU);
    int*   col_ub = (int*)alloc(E_UB);  float* w_ub = (float*)alloc(E_UB);
    int*   col_bb = (int*)alloc(E_BB);  float* w_bb = (float*)alloc(E_BB);
    int*   cnt    = (int*)alloc(2 * N_U + 2 * N_B);
    int*   rp_bu  = (int*)alloc(N_U + 1);
    int*   rp_uu  = (int*)alloc(N_U + 1);
    int*   rp_ub  = (int*)alloc(N_B + 1);
    int*   rp_bb  = (int*)alloc(N_B + 1);

    int* cnt_bu = cnt;
    int* cnt_uu = cnt + N_U;
    int* cnt_ub = cnt + 2 * N_U;
    int* cnt_bb = cnt + 2 * N_U + N_B;

    hipMemsetAsync(cnt, 0, sizeof(int) * (2 * N_U + 2 * N_B), stream);

    // histogram by destination
    count_kernel<<<2048, 256, 0, stream>>>(ub_u,   E_UB, cnt_bu);
    count_kernel<<<1024, 256, 0, stream>>>(uu_dst, E_UU, cnt_uu);
    count_kernel<<<2048, 256, 0, stream>>>(ub_b,   E_UB, cnt_ub);
    count_kernel<<<512,  256, 0, stream>>>(bb_dst, E_BB, cnt_bb);

    // exclusive scans (cursor aliases cnt)
    scan_kernel<<<1, 1024, 0, stream>>>(cnt_bu, N_U, rp_bu, cnt_bu);
    scan_kernel<<<1, 1024, 0, stream>>>(cnt_uu, N_U, rp_uu, cnt_uu);
    scan_kernel<<<1, 1024, 0, stream>>>(cnt_ub, N_B, rp_ub, cnt_ub);
    scan_kernel<<<1, 1024, 0, stream>>>(cnt_bb, N_B, rp_bb, cnt_bb);

    // scatter edges into CSR order
    fill_kernel<<<2048, 256, 0, stream>>>(ub_b,   ub_u,   val_bu, E_UB, cnt_bu, col_bu, w_bu);
    fill_kernel<<<1024, 256, 0, stream>>>(uu_src, uu_dst, uu_val, E_UU, cnt_uu, col_uu, w_uu);
    fill_kernel<<<2048, 256, 0, stream>>>(ub_u,   ub_b,   val_ub, E_UB, cnt_ub, col_ub, w_ub);
    fill_kernel<<<512,  256, 0, stream>>>(bb_src, bb_dst, bb_val, E_BB, cnt_bb, col_bb, w_bb);

    // input projections (also initialize running sums)
    gemm_kernel<<<(N_U + 7) / 8, 256, 0, stream>>>(user_feat, W_user, N_U, u_cur, u_sum);
    gemm_kernel<<<(N_B + 7) / 8, 256, 0, stream>>>(biz_feat,  W_biz,  N_B, b_cur, b_sum);

    // propagation layers
    for (int l = 0; l < 3; ++l) {
        spmm_first <<<(N_U + 3) / 4, 256, 0, stream>>>(rp_bu, col_bu, w_bu, b_cur, u_nxt, N_U);
        spmm_second<<<(N_U + 3) / 4, 256, 0, stream>>>(rp_uu, col_uu, w_uu, u_cur, u_nxt, u_sum, N_U);
        spmm_first <<<(N_B + 3) / 4, 256, 0, stream>>>(rp_ub, col_ub, w_ub, u_cur, b_nxt, N_B);
        spmm_second<<<(N_B + 3) / 4, 256, 0, stream>>>(rp_bb, col_bb, w_bb, b_cur, b_nxt, b_sum, N_B);
        float* t;
        t = u_cur; u_cur = u_nxt; u_nxt = t;
        t = b_cur; b_cur = b_nxt; b_nxt = t;
    }

    norm_kernel<<<(N_U + 3) / 4, 256, 0, stream>>>(u_sum, N_U);
    norm_kernel<<<(N_B + 3) / 4, 256, 0, stream>>>(b_sum, N_B);
}

// Round 2
// 4342.449 us; speedup vs baseline: 1.0510x; 1.0510x over previous
//
#include <hip/hip_runtime.h>

#define N_U 100000
#define N_B 20000
#define E_UB 3200000
#define E_UU 1600000
#define E_BB 320000
#define IN_DIM 384
#define D 128

// ---------------- bf16 helpers ----------------

__device__ __forceinline__ unsigned bf16pack(float a, float b) {
    unsigned ua = __float_as_uint(a);
    unsigned ub = __float_as_uint(b);
    unsigned ra = (ua + 0x7fffu + ((ua >> 16) & 1u)) >> 16;
    unsigned rb = (ub + 0x7fffu + ((ub >> 16) & 1u)) >> 16;
    return ra | (rb << 16);
}

// ---------------- CSR build ----------------

__global__ void count_kernel(const int* __restrict__ dst, int n, int* __restrict__ cnt) {
    int i = blockIdx.x * blockDim.x + threadIdx.x;
    int stride = gridDim.x * blockDim.x;
    for (; i < n; i += stride) atomicAdd(&cnt[dst[i]], 1);
}

__global__ void scan_kernel(int* __restrict__ cnt, int n,
                            int* __restrict__ rowptr, int* __restrict__ cursor) {
    __shared__ int sh[1024];
    int t = threadIdx.x;
    int seg = (n + 1023) >> 10;
    int lo = t * seg;
    int hi = min(n, lo + seg);
    int s = 0;
    for (int i = lo; i < hi; ++i) s += cnt[i];
    sh[t] = s;
    __syncthreads();
    for (int off = 1; off < 1024; off <<= 1) {
        int add = 0;
        if (t >= off) add = sh[t - off];
        __syncthreads();
        sh[t] += add;
        __syncthreads();
    }
    int run = sh[t] - s;
    for (int i = lo; i < hi; ++i) {
        int c = cnt[i];
        rowptr[i] = run;
        cursor[i] = run;  // aliases cnt[i]; c already read
        run += c;
    }
    if (t == 1023) rowptr[n] = sh[1023];
}

__global__ void fill_kernel(const int* __restrict__ src, const int* __restrict__ dst,
                            const float* __restrict__ val, int n,
                            int* __restrict__ cursor, int2* __restrict__ edges) {
    int i = blockIdx.x * blockDim.x + threadIdx.x;
    int stride = gridDim.x * blockDim.x;
    for (; i < n; i += stride) {
        int d = dst[i];
        int idx = atomicAdd(&cursor[d], 1);
        int2 e;
        e.x = src[i];
        e.y = __float_as_int(val[i]);
        edges[idx] = e;
    }
}

// ---------------- dense GEMM: cur(bf16) and sum(fp32) = X[n,384] @ W[384,128] ----------------

__global__ void gemm_kernel(const float* __restrict__ X, const float* __restrict__ W, int n,
                            unsigned* __restrict__ curh, float* __restrict__ sum) {
    __shared__ float sx[8 * IN_DIM];
    int base = blockIdx.x * 8;
    for (int i = threadIdx.x; i < 8 * IN_DIM; i += 256) {
        int r = base + i / IN_DIM;
        sx[i] = (r < n) ? X[(size_t)r * IN_DIM + (i % IN_DIM)] : 0.f;
    }
    __syncthreads();
    int col = threadIdx.x & 127;
    int rh  = threadIdx.x >> 7;  // 0 or 1
    float acc[4] = {0.f, 0.f, 0.f, 0.f};
    for (int k = 0; k < IN_DIM; ++k) {
        float wv = W[k * D + col];
#pragma unroll
        for (int j = 0; j < 4; ++j)
            acc[j] += sx[(rh * 4 + j) * IN_DIM + k] * wv;
    }
#pragma unroll
    for (int j = 0; j < 4; ++j) {
        int r = base + rh * 4 + j;
        if (r < n) {
            size_t o = (size_t)r * D + col;
            sum[o] = acc[j];
            // bf16 store: each thread owns one scalar; pack via 16-bit store
            unsigned ua = __float_as_uint(acc[j]);
            unsigned hr = (ua + 0x7fffu + ((ua >> 16) & 1u)) >> 16;
            ((unsigned short*)curh)[o] = (unsigned short)hr;
        }
    }
}

// ---------------- fused pull SpMM: y_nxt[r] = A1@x1 + A2@x2 ; sum += acc ----------------
// One wave per dst row; lane holds 2 bf16 components (one uint). x rows are 64 uints.

__global__ void spmm_fused(const int* __restrict__ rp1, const int2* __restrict__ e1,
                           const int* __restrict__ rp2, const int2* __restrict__ e2,
                           const unsigned* __restrict__ x1, const unsigned* __restrict__ x2,
                           unsigned* __restrict__ y_nxt, float* __restrict__ sum, int n) {
    int wave = threadIdx.x >> 6;
    int lane = threadIdx.x & 63;
    int r = blockIdx.x * 4 + wave;
    if (r >= n) return;
    float ax = 0.f, ay = 0.f;

    int s = rp1[r], e = rp1[r + 1];
    for (int i = s; i < e; ++i) {
        int2 ed = e1[i];
        float w = __int_as_float(ed.y);
        unsigned u = x1[(size_t)ed.x * 64 + lane];
        ax += w * __uint_as_float(u << 16);
        ay += w * __uint_as_float(u & 0xffff0000u);
    }
    s = rp2[r]; e = rp2[r + 1];
    for (int i = s; i < e; ++i) {
        int2 ed = e2[i];
        float w = __int_as_float(ed.y);
        unsigned u = x2[(size_t)ed.x * 64 + lane];
        ax += w * __uint_as_float(u << 16);
        ay += w * __uint_as_float(u & 0xffff0000u);
    }

    size_t o = (size_t)r * 64 + lane;
    y_nxt[o] = bf16pack(ax, ay);
    float2* sp = (float2*)sum + o;
    float2 sv = *sp;
    sv.x += ax;
    sv.y += ay;
    *sp = sv;
}

// ---------------- normalize: v = sum*0.25; v / max(||v||,1e-12), in place ----------------

__global__ void norm_kernel(float* __restrict__ out, int n) {
    int wave = threadIdx.x >> 6;
    int lane = threadIdx.x & 63;
    int r = blockIdx.x * 4 + wave;
    if (r >= n) return;
    float2* p = (float2*)out + (size_t)r * 64 + lane;
    float2 v = *p;
    v.x *= 0.25f;
    v.y *= 0.25f;
    float ss = v.x * v.x + v.y * v.y;
    for (int off = 32; off > 0; off >>= 1) ss += __shfl_down(ss, off);
    ss = __shfl(ss, 0);
    float inv = 1.f / fmaxf(sqrtf(ss), 1e-12f);
    v.x *= inv;
    v.y *= inv;
    *p = v;
}

// ---------------- launch ----------------

extern "C" void kernel_launch(void* const* d_in, const int* in_sizes, int n_in,
                              void* d_out, int out_size, void* d_ws, size_t ws_size,
                              hipStream_t stream) {
    const float* user_feat = (const float*)d_in[0];
    const float* biz_feat  = (const float*)d_in[1];
    const float* W_user    = (const float*)d_in[2];
    const float* W_biz     = (const float*)d_in[3];
    const int*   ub_u      = (const int*)d_in[4];
    const int*   ub_b      = (const int*)d_in[5];
    const float* val_ub    = (const float*)d_in[6];
    const float* val_bu    = (const float*)d_in[7];
    const int*   uu_src    = (const int*)d_in[8];
    const int*   uu_dst    = (const int*)d_in[9];
    const float* uu_val    = (const float*)d_in[10];
    const int*   bb_src    = (const int*)d_in[11];
    const int*   bb_dst    = (const int*)d_in[12];
    const float* bb_val    = (const float*)d_in[13];

    float* out   = (float*)d_out;
    float* u_sum = out;                      // [N_U, D] fp32
    float* b_sum = out + (size_t)N_U * D;    // [N_B, D] fp32

    char* ws = (char*)d_ws;
    size_t off = 0;
    auto alloc = [&](size_t bytes) -> void* {
        void* p = ws + off;
        off += (bytes + 255) & ~(size_t)255;
        return p;
    };
    unsigned* u_curh = (unsigned*)alloc((size_t)N_U * 64 * 4);  // bf16 [N_U,128] as uints
    unsigned* u_nxth = (unsigned*)alloc((size_t)N_U * 64 * 4);
    unsigned* b_curh = (unsigned*)alloc((size_t)N_B * 64 * 4);
    unsigned* b_nxth = (unsigned*)alloc((size_t)N_B * 64 * 4);
    int2* e_bu = (int2*)alloc((size_t)E_UB * 8);
    int2* e_uu = (int2*)alloc((size_t)E_UU * 8);
    int2* e_ub = (int2*)alloc((size_t)E_UB * 8);
    int2* e_bb = (int2*)alloc((size_t)E_BB * 8);
    int*  cnt  = (int*)alloc((2 * N_U + 2 * N_B) * 4);
    int*  rp_bu = (int*)alloc((N_U + 1) * 4);
    int*  rp_uu = (int*)alloc((N_U + 1) * 4);
    int*  rp_ub = (int*)alloc((N_B + 1) * 4);
    int*  rp_bb = (int*)alloc((N_B + 1) * 4);

    int* cnt_bu = cnt;
    int* cnt_uu = cnt + N_U;
    int* cnt_ub = cnt + 2 * N_U;
    int* cnt_bb = cnt + 2 * N_U + N_B;

    hipMemsetAsync(cnt, 0, sizeof(int) * (2 * N_U + 2 * N_B), stream);

    // histogram by destination
    count_kernel<<<2048, 256, 0, stream>>>(ub_u,   E_UB, cnt_bu);
    count_kernel<<<1024, 256, 0, stream>>>(uu_dst, E_UU, cnt_uu);
    count_kernel<<<2048, 256, 0, stream>>>(ub_b,   E_UB, cnt_ub);
    count_kernel<<<512,  256, 0, stream>>>(bb_dst, E_BB, cnt_bb);

    // exclusive scans (cursor aliases cnt)
    scan_kernel<<<1, 1024, 0, stream>>>(cnt_bu, N_U, rp_bu, cnt_bu);
    scan_kernel<<<1, 1024, 0, stream>>>(cnt_uu, N_U, rp_uu, cnt_uu);
    scan_kernel<<<1, 1024, 0, stream>>>(cnt_ub, N_B, rp_ub, cnt_ub);
    scan_kernel<<<1, 1024, 0, stream>>>(cnt_bb, N_B, rp_bb, cnt_bb);

    // scatter edges into CSR order (int2 {col, val_bits})
    fill_kernel<<<2048, 256, 0, stream>>>(ub_b,   ub_u,   val_bu, E_UB, cnt_bu, e_bu);
    fill_kernel<<<1024, 256, 0, stream>>>(uu_src, uu_dst, uu_val, E_UU, cnt_uu, e_uu);
    fill_kernel<<<2048, 256, 0, stream>>>(ub_u,   ub_b,   val_ub, E_UB, cnt_ub, e_ub);
    fill_kernel<<<512,  256, 0, stream>>>(bb_src, bb_dst, bb_val, E_BB, cnt_bb, e_bb);

    // input projections: init sum (fp32, in d_out) + cur (bf16)
    gemm_kernel<<<(N_U + 7) / 8, 256, 0, stream>>>(user_feat, W_user, N_U, u_curh, u_sum);
    gemm_kernel<<<(N_B + 7) / 8, 256, 0, stream>>>(biz_feat,  W_biz,  N_B, b_curh, b_sum);

    // propagation layers (fused: u_new = bu@b + uu@u ; b_new = ub@u + bb@b)
    for (int l = 0; l < 3; ++l) {
        spmm_fused<<<(N_U + 3) / 4, 256, 0, stream>>>(rp_bu, e_bu, rp_uu, e_uu,
                                                      b_curh, u_curh, u_nxth, u_sum, N_U);
        spmm_fused<<<(N_B + 3) / 4, 256, 0, stream>>>(rp_ub, e_ub, rp_bb, e_bb,
                                                      u_curh, b_curh, b_nxth, b_sum, N_B);
        unsigned* t;
        t = u_curh; u_curh = u_nxth; u_nxth = t;
        t = b_curh; b_curh = b_nxth; b_nxth = t;
    }

    norm_kernel<<<(N_U + 3) / 4, 256, 0, stream>>>(u_sum, N_U);
    norm_kernel<<<(N_B + 3) / 4, 256, 0, stream>>>(b_sum, N_B);
}

// Round 3
// 2894.144 us; speedup vs baseline: 1.5770x; 1.5004x over previous
//
#include <hip/hip_runtime.h>

#define N_U 100000
#define N_B 20000
#define E_UB 3200000
#define E_UU 1600000
#define E_BB 320000
#define IN_DIM 384
#define D 128

// ---------------- bf16 helpers ----------------

__device__ __forceinline__ unsigned bf16rn(float a) {
    unsigned ua = __float_as_uint(a);
    return (ua + 0x7fffu + ((ua >> 16) & 1u)) >> 16;
}

__device__ __forceinline__ void fma8(float* a, float w, uint4 u) {
    a[0] += w * __uint_as_float(u.x << 16);
    a[1] += w * __uint_as_float(u.x & 0xffff0000u);
    a[2] += w * __uint_as_float(u.y << 16);
    a[3] += w * __uint_as_float(u.y & 0xffff0000u);
    a[4] += w * __uint_as_float(u.z << 16);
    a[5] += w * __uint_as_float(u.z & 0xffff0000u);
    a[6] += w * __uint_as_float(u.w << 16);
    a[7] += w * __uint_as_float(u.w & 0xffff0000u);
}

// ---------------- CSR build ----------------

__global__ void count_kernel(const int* __restrict__ dst, int n, int* __restrict__ cnt) {
    int i = blockIdx.x * blockDim.x + threadIdx.x;
    int stride = gridDim.x * blockDim.x;
    for (; i < n; i += stride) atomicAdd(&cnt[dst[i]], 1);
}

__global__ void scan_kernel(int* __restrict__ cnt, int n,
                            int* __restrict__ rowptr, int* __restrict__ cursor) {
    __shared__ int sh[1024];
    int t = threadIdx.x;
    int seg = (n + 1023) >> 10;
    int lo = t * seg;
    int hi = min(n, lo + seg);
    int s = 0;
    for (int i = lo; i < hi; ++i) s += cnt[i];
    sh[t] = s;
    __syncthreads();
    for (int off = 1; off < 1024; off <<= 1) {
        int add = 0;
        if (t >= off) add = sh[t - off];
        __syncthreads();
        sh[t] += add;
        __syncthreads();
    }
    int run = sh[t] - s;
    for (int i = lo; i < hi; ++i) {
        int c = cnt[i];
        rowptr[i] = run;
        cursor[i] = run;  // aliases cnt[i]; c already read
        run += c;
    }
    if (t == 1023) rowptr[n] = sh[1023];
}

__global__ void fill_kernel(const int* __restrict__ src, const int* __restrict__ dst,
                            const float* __restrict__ val, int n,
                            int* __restrict__ cursor, int2* __restrict__ edges) {
    int i = blockIdx.x * blockDim.x + threadIdx.x;
    int stride = gridDim.x * blockDim.x;
    for (; i < n; i += stride) {
        int d = dst[i];
        int idx = atomicAdd(&cursor[d], 1);
        int2 e;
        e.x = src[i];
        e.y = __float_as_int(val[i]);
        edges[idx] = e;
    }
}

// ---------------- dense GEMM: cur(bf16) and sum(fp32) = X[n,384] @ W[384,128] ----------------

__global__ void gemm_kernel(const float* __restrict__ X, const float* __restrict__ W, int n,
                            unsigned* __restrict__ curh, float* __restrict__ sum) {
    __shared__ float sx[8 * IN_DIM];
    int base = blockIdx.x * 8;
    for (int i = threadIdx.x; i < 8 * IN_DIM; i += 256) {
        int r = base + i / IN_DIM;
        sx[i] = (r < n) ? X[(size_t)r * IN_DIM + (i % IN_DIM)] : 0.f;
    }
    __syncthreads();
    int col = threadIdx.x & 127;
    int rh  = threadIdx.x >> 7;  // 0 or 1
    float acc[4] = {0.f, 0.f, 0.f, 0.f};
    for (int k = 0; k < IN_DIM; ++k) {
        float wv = W[k * D + col];
#pragma unroll
        for (int j = 0; j < 4; ++j)
            acc[j] += sx[(rh * 4 + j) * IN_DIM + k] * wv;
    }
#pragma unroll
    for (int j = 0; j < 4; ++j) {
        int r = base + rh * 4 + j;
        if (r < n) {
            size_t o = (size_t)r * D + col;
            sum[o] = acc[j];
            ((unsigned short*)curh)[o] = (unsigned short)bf16rn(acc[j]);
        }
    }
}

// ---------------- fused pull SpMM v2 ----------------
// One wave per dst row. Wave split into 4 quarters (16 lanes), each quarter owns one
// edge; each lane gathers uint4 (16B) of the 256B bf16 source row -> 1KB per gather
// instruction covering 4 edges. Unroll x2 -> 2 gathers in flight per wave.
// acc: 8 fp32 components per lane (comps 8l..8l+7); reduce across quarters at end.

__global__ void spmm_fused(const int* __restrict__ rp1, const int2* __restrict__ e1,
                           const int* __restrict__ rp2, const int2* __restrict__ e2,
                           const uint4* __restrict__ x1, const uint4* __restrict__ x2,
                           uint4* __restrict__ y_nxt, float4* __restrict__ sum, int n) {
    int wave = threadIdx.x >> 6;
    int lane = threadIdx.x & 63;
    int q = lane >> 4;       // 0..3 quarter
    int l = lane & 15;       // lane in quarter
    int r = blockIdx.x * 4 + wave;
    if (r >= n) return;

    float acc[8];
#pragma unroll
    for (int k = 0; k < 8; ++k) acc[k] = 0.f;

#pragma unroll
    for (int pass = 0; pass < 2; ++pass) {
        const int* rp = pass ? rp2 : rp1;
        const int2* edges = pass ? e2 : e1;
        const uint4* xv = pass ? x2 : x1;
        int s = rp[r], e = rp[r + 1];
        int i = s;
        for (; i + 8 <= e; i += 8) {
            int2 edA = edges[i + q];
            int2 edB = edges[i + 4 + q];
            uint4 uA = xv[(size_t)edA.x * 16 + l];
            uint4 uB = xv[(size_t)edB.x * 16 + l];
            fma8(acc, __int_as_float(edA.y), uA);
            fma8(acc, __int_as_float(edB.y), uB);
        }
        if (i < e) {
            int idx = i + q;
            bool valid = idx < e;
            int2 ed = edges[valid ? idx : (e - 1)];
            uint4 u = xv[(size_t)ed.x * 16 + l];
            fma8(acc, valid ? __int_as_float(ed.y) : 0.f, u);
            i += 4;
            if (i < e) {
                idx = i + q;
                valid = idx < e;
                int2 ed2 = edges[valid ? idx : (e - 1)];
                uint4 u2 = xv[(size_t)ed2.x * 16 + l];
                fma8(acc, valid ? __int_as_float(ed2.y) : 0.f, u2);
            }
        }
    }

    // reduce across quarters: lanes {l, l+16, l+32, l+48} hold same components
#pragma unroll
    for (int k = 0; k < 8; ++k) {
        acc[k] += __shfl_xor(acc[k], 16);
        acc[k] += __shfl_xor(acc[k], 32);
    }

    if (q == 0) {
        // y_nxt row: 16 uint4 (256B bf16)
        uint4 p;
        p.x = bf16rn(acc[0]) | (bf16rn(acc[1]) << 16);
        p.y = bf16rn(acc[2]) | (bf16rn(acc[3]) << 16);
        p.z = bf16rn(acc[4]) | (bf16rn(acc[5]) << 16);
        p.w = bf16rn(acc[6]) | (bf16rn(acc[7]) << 16);
        y_nxt[(size_t)r * 16 + l] = p;
        // sum row: 32 float4 (512B fp32); this lane owns float4 indices 2l, 2l+1
        float4* sp = sum + (size_t)r * 32 + 2 * l;
        float4 s0 = sp[0], s1 = sp[1];
        s0.x += acc[0]; s0.y += acc[1]; s0.z += acc[2]; s0.w += acc[3];
        s1.x += acc[4]; s1.y += acc[5]; s1.z += acc[6]; s1.w += acc[7];
        sp[0] = s0; sp[1] = s1;
    }
}

// ---------------- normalize: v = sum*0.25; v / max(||v||,1e-12), in place ----------------

__global__ void norm_kernel(float* __restrict__ out, int n) {
    int wave = threadIdx.x >> 6;
    int lane = threadIdx.x & 63;
    int r = blockIdx.x * 4 + wave;
    if (r >= n) return;
    float2* p = (float2*)out + (size_t)r * 64 + lane;
    float2 v = *p;
    v.x *= 0.25f;
    v.y *= 0.25f;
    float ss = v.x * v.x + v.y * v.y;
    for (int off = 32; off > 0; off >>= 1) ss += __shfl_down(ss, off);
    ss = __shfl(ss, 0);
    float inv = 1.f / fmaxf(sqrtf(ss), 1e-12f);
    v.x *= inv;
    v.y *= inv;
    *p = v;
}

// ---------------- launch ----------------

extern "C" void kernel_launch(void* const* d_in, const int* in_sizes, int n_in,
                              void* d_out, int out_size, void* d_ws, size_t ws_size,
                              hipStream_t stream) {
    const float* user_feat = (const float*)d_in[0];
    const float* biz_feat  = (const float*)d_in[1];
    const float* W_user    = (const float*)d_in[2];
    const float* W_biz     = (const float*)d_in[3];
    const int*   ub_u      = (const int*)d_in[4];
    const int*   ub_b      = (const int*)d_in[5];
    const float* val_ub    = (const float*)d_in[6];
    const float* val_bu    = (const float*)d_in[7];
    const int*   uu_src    = (const int*)d_in[8];
    const int*   uu_dst    = (const int*)d_in[9];
    const float* uu_val    = (const float*)d_in[10];
    const int*   bb_src    = (const int*)d_in[11];
    const int*   bb_dst    = (const int*)d_in[12];
    const float* bb_val    = (const float*)d_in[13];

    float* out   = (float*)d_out;
    float* u_sum = out;                      // [N_U, D] fp32
    float* b_sum = out + (size_t)N_U * D;    // [N_B, D] fp32

    char* ws = (char*)d_ws;
    size_t off = 0;
    auto alloc = [&](size_t bytes) -> void* {
        void* p = ws + off;
        off += (bytes + 255) & ~(size_t)255;
        return p;
    };
    unsigned* u_curh = (unsigned*)alloc((size_t)N_U * 64 * 4);  // bf16 [N_U,128]
    unsigned* u_nxth = (unsigned*)alloc((size_t)N_U * 64 * 4);
    unsigned* b_curh = (unsigned*)alloc((size_t)N_B * 64 * 4);
    unsigned* b_nxth = (unsigned*)alloc((size_t)N_B * 64 * 4);
    int2* e_bu = (int2*)alloc((size_t)E_UB * 8);
    int2* e_uu = (int2*)alloc((size_t)E_UU * 8);
    int2* e_ub = (int2*)alloc((size_t)E_UB * 8);
    int2* e_bb = (int2*)alloc((size_t)E_BB * 8);
    int*  cnt  = (int*)alloc((2 * N_U + 2 * N_B) * 4);
    int*  rp_bu = (int*)alloc((N_U + 1) * 4);
    int*  rp_uu = (int*)alloc((N_U + 1) * 4);
    int*  rp_ub = (int*)alloc((N_B + 1) * 4);
    int*  rp_bb = (int*)alloc((N_B + 1) * 4);

    int* cnt_bu = cnt;
    int* cnt_uu = cnt + N_U;
    int* cnt_ub = cnt + 2 * N_U;
    int* cnt_bb = cnt + 2 * N_U + N_B;

    hipMemsetAsync(cnt, 0, sizeof(int) * (2 * N_U + 2 * N_B), stream);

    // histogram by destination
    count_kernel<<<2048, 256, 0, stream>>>(ub_u,   E_UB, cnt_bu);
    count_kernel<<<1024, 256, 0, stream>>>(uu_dst, E_UU, cnt_uu);
    count_kernel<<<2048, 256, 0, stream>>>(ub_b,   E_UB, cnt_ub);
    count_kernel<<<512,  256, 0, stream>>>(bb_dst, E_BB, cnt_bb);

    // exclusive scans (cursor aliases cnt)
    scan_kernel<<<1, 1024, 0, stream>>>(cnt_bu, N_U, rp_bu, cnt_bu);
    scan_kernel<<<1, 1024, 0, stream>>>(cnt_uu, N_U, rp_uu, cnt_uu);
    scan_kernel<<<1, 1024, 0, stream>>>(cnt_ub, N_B, rp_ub, cnt_ub);
    scan_kernel<<<1, 1024, 0, stream>>>(cnt_bb, N_B, rp_bb, cnt_bb);

    // scatter edges into CSR order (int2 {col, val_bits})
    fill_kernel<<<2048, 256, 0, stream>>>(ub_b,   ub_u,   val_bu, E_UB, cnt_bu, e_bu);
    fill_kernel<<<1024, 256, 0, stream>>>(uu_src, uu_dst, uu_val, E_UU, cnt_uu, e_uu);
    fill_kernel<<<2048, 256, 0, stream>>>(ub_u,   ub_b,   val_ub, E_UB, cnt_ub, e_ub);
    fill_kernel<<<512,  256, 0, stream>>>(bb_src, bb_dst, bb_val, E_BB, cnt_bb, e_bb);

    // input projections: init sum (fp32, in d_out) + cur (bf16)
    gemm_kernel<<<(N_U + 7) / 8, 256, 0, stream>>>(user_feat, W_user, N_U, u_curh, u_sum);
    gemm_kernel<<<(N_B + 7) / 8, 256, 0, stream>>>(biz_feat,  W_biz,  N_B, b_curh, b_sum);

    // propagation layers (fused: u_new = bu@b + uu@u ; b_new = ub@u + bb@b)
    for (int l = 0; l < 3; ++l) {
        spmm_fused<<<(N_U + 3) / 4, 256, 0, stream>>>(rp_bu, e_bu, rp_uu, e_uu,
                                                      (const uint4*)b_curh, (const uint4*)u_curh,
                                                      (uint4*)u_nxth, (float4*)u_sum, N_U);
        spmm_fused<<<(N_B + 3) / 4, 256, 0, stream>>>(rp_ub, e_ub, rp_bb, e_bb,
                                                      (const uint4*)u_curh, (const uint4*)b_curh,
                                                      (uint4*)b_nxth, (float4*)b_sum, N_B);
        unsigned* t;
        t = u_curh; u_curh = u_nxth; u_nxth = t;
        t = b_curh; b_curh = b_nxth; b_nxth = t;
    }

    norm_kernel<<<(N_U + 3) / 4, 256, 0, stream>>>(u_sum, N_U);
    norm_kernel<<<(N_B + 3) / 4, 256, 0, stream>>>(b_sum, N_B);
}

// Round 4
// 2638.714 us; speedup vs baseline: 1.7297x; 1.0968x over previous
//
#include <hip/hip_runtime.h>

#define N_U 100000
#define N_B 20000
#define E_UB 3200000
#define E_UU 1600000
#define E_BB 320000
#define IN_DIM 384
#define D 128

// graph order: 0=bu (dst=ub_u), 1=uu (dst=uu_dst), 2=ub (dst=ub_b), 3=bb (dst=bb_dst)
#define B1 E_UB
#define B2 (E_UB + E_UU)
#define B3 (E_UB + E_UU + E_UB)
#define E_TOT (E_UB + E_UU + E_UB + E_BB)

// bucket shifts (rows per bucket = 1<<shift)
#define SH0 6   // bu: 64 rows -> avg 2048 edges/bucket
#define SH1 7   // uu: 128 rows -> avg 2048
#define SH2 4   // ub: 16 rows -> avg 2560
#define SH3 7   // bb: 128 rows -> avg 2048
#define NB0 1563  // ceil(100000/64)
#define NB1 782   // ceil(100000/128)
#define NB2 1250  // 20000/16
#define NB3 157   // ceil(20000/128)
#define C1 NB0
#define C2 (NB0 + NB1)
#define C3 (NB0 + NB1 + NB2)
#define NB_TOT (NB0 + NB1 + NB2 + NB3)

// ---------------- bf16 helpers ----------------

__device__ __forceinline__ unsigned bf16rn(float a) {
    unsigned ua = __float_as_uint(a);
    return (ua + 0x7fffu + ((ua >> 16) & 1u)) >> 16;
}

__device__ __forceinline__ void fma8(float* a, float w, uint4 u) {
    a[0] += w * __uint_as_float(u.x << 16);
    a[1] += w * __uint_as_float(u.x & 0xffff0000u);
    a[2] += w * __uint_as_float(u.y << 16);
    a[3] += w * __uint_as_float(u.y & 0xffff0000u);
    a[4] += w * __uint_as_float(u.z << 16);
    a[5] += w * __uint_as_float(u.z & 0xffff0000u);
    a[6] += w * __uint_as_float(u.w << 16);
    a[7] += w * __uint_as_float(u.w & 0xffff0000u);
}

// ---------------- CSR build ----------------

__global__ void count_all(const int* __restrict__ d0, const int* __restrict__ d1,
                          const int* __restrict__ d2, const int* __restrict__ d3,
                          int* __restrict__ cnt) {
    int stride = gridDim.x * blockDim.x;
    for (int gi = blockIdx.x * blockDim.x + threadIdx.x; gi < E_TOT; gi += stride) {
        if (gi < B1)       atomicAdd(&cnt[d0[gi]], 1);
        else if (gi < B2)  atomicAdd(&cnt[N_U + d1[gi - B1]], 1);
        else if (gi < B3)  atomicAdd(&cnt[2 * N_U + d2[gi - B2]], 1);
        else               atomicAdd(&cnt[2 * N_U + N_B + d3[gi - B3]], 1);
    }
}

// one block per graph; exclusive scan cnt -> rowptr, cursor copy left in cnt
__global__ void scan4(int* c0, int* r0, int* c1, int* r1,
                      int* c2, int* r2, int* c3, int* r3) {
    __shared__ int sh[1024];
    int* cnt; int* rowptr; int n;
    switch (blockIdx.x) {
        case 0: cnt = c0; rowptr = r0; n = N_U; break;
        case 1: cnt = c1; rowptr = r1; n = N_U; break;
        case 2: cnt = c2; rowptr = r2; n = N_B; break;
        default: cnt = c3; rowptr = r3; n = N_B; break;
    }
    int t = threadIdx.x;
    int seg = (n + 1023) >> 10;
    int lo = t * seg;
    int hi = min(n, lo + seg);
    int s = 0;
    for (int i = lo; i < hi; ++i) s += cnt[i];
    sh[t] = s;
    __syncthreads();
    for (int off = 1; off < 1024; off <<= 1) {
        int add = 0;
        if (t >= off) add = sh[t - off];
        __syncthreads();
        sh[t] += add;
        __syncthreads();
    }
    int run = sh[t] - s;
    for (int i = lo; i < hi; ++i) {
        int c = cnt[i];
        rowptr[i] = run;
        cnt[i] = run;   // cursor copy (fallback path)
        run += c;
    }
    if (t == 1023) rowptr[n] = sh[1023];
}

// init per-bucket append cursors from rowptr
__global__ void binit(const int* __restrict__ r0, const int* __restrict__ r1,
                      const int* __restrict__ r2, const int* __restrict__ r3,
                      int* __restrict__ bcur) {
    int stride = gridDim.x * blockDim.x;
    for (int i = blockIdx.x * blockDim.x + threadIdx.x; i < NB_TOT; i += stride) {
        if (i < C1)       bcur[i] = r0[i << SH0];
        else if (i < C2)  bcur[i] = r1[(i - C1) << SH1];
        else if (i < C3)  bcur[i] = r2[(i - C2) << SH2];
        else              bcur[i] = r3[(i - C3) << SH3];
    }
}

// Phase A: append edges into bucket-contiguous staging (sequential write fronts)
__global__ void phaseA(const int* __restrict__ d0, const int* __restrict__ s0, const float* __restrict__ v0,
                       const int* __restrict__ d1, const int* __restrict__ s1, const float* __restrict__ v1,
                       const int* __restrict__ d2, const int* __restrict__ s2, const float* __restrict__ v2,
                       const int* __restrict__ d3, const int* __restrict__ s3, const float* __restrict__ v3,
                       int* __restrict__ bcur, int2* __restrict__ st8, unsigned char* __restrict__ st1) {
    int stride = gridDim.x * blockDim.x;
    for (int gi = blockIdx.x * blockDim.x + threadIdx.x; gi < E_TOT; gi += stride) {
        const int* dst; const int* src; const float* val;
        int li, shift, ebase, bbase;
        if (gi < B1)      { dst = d0; src = s0; val = v0; li = gi;      shift = SH0; ebase = 0;  bbase = 0;  }
        else if (gi < B2) { dst = d1; src = s1; val = v1; li = gi - B1; shift = SH1; ebase = B1; bbase = C1; }
        else if (gi < B3) { dst = d2; src = s2; val = v2; li = gi - B2; shift = SH2; ebase = B2; bbase = C2; }
        else              { dst = d3; src = s3; val = v3; li = gi - B3; shift = SH3; ebase = B3; bbase = C3; }
        int d = dst[li];
        int k = d >> shift;
        int pos = atomicAdd(&bcur[bbase + k], 1);
        int2 e;
        e.x = src[li];
        e.y = __float_as_int(val[li]);
        st8[ebase + pos] = e;
        st1[ebase + pos] = (unsigned char)(d - (k << shift));
    }
}

// Phase B: per-bucket in-LDS counting sort, coalesced write to final CSR
__global__ __launch_bounds__(256) void phaseB(
        const int* __restrict__ r0, const int* __restrict__ r1,
        const int* __restrict__ r2, const int* __restrict__ r3,
        int2* __restrict__ e0, int2* __restrict__ e1,
        int2* __restrict__ e2, int2* __restrict__ e3,
        int* __restrict__ gc0, int* __restrict__ gc1,
        int* __restrict__ gc2, int* __restrict__ gc3,
        const int2* __restrict__ st8, const unsigned char* __restrict__ st1) {
    __shared__ int2 lde[4096];
    __shared__ int lcur[128];
    int b = blockIdx.x;
    const int* rp; int2* eo; int* gc;
    int k, n, shift, ebase;
    if (b < C1)       { k = b;      rp = r0; eo = e0; gc = gc0; n = N_U; shift = SH0; ebase = 0;  }
    else if (b < C2)  { k = b - C1; rp = r1; eo = e1; gc = gc1; n = N_U; shift = SH1; ebase = B1; }
    else if (b < C3)  { k = b - C2; rp = r2; eo = e2; gc = gc2; n = N_B; shift = SH2; ebase = B2; }
    else              { k = b - C3; rp = r3; eo = e3; gc = gc3; n = N_B; shift = SH3; ebase = B3; }
    int lo = k << shift;
    int hi = min(n, lo + (1 << shift));
    int base = rp[lo];
    int cnt = rp[hi] - base;
    int rows = hi - lo;
    for (int j = threadIdx.x; j < rows; j += 256) lcur[j] = rp[lo + j] - base;
    __syncthreads();
    if (cnt <= 4096) {
        for (int i = threadIdx.x; i < cnt; i += 256) {
            int2 ed = st8[ebase + base + i];
            int dl = st1[ebase + base + i];
            int p = atomicAdd(&lcur[dl], 1);
            lde[p] = ed;
        }
        __syncthreads();
        for (int i = threadIdx.x; i < cnt; i += 256) eo[base + i] = lde[i];
    } else {
        // fallback: global cursors (cnt array holds rowptr copies)
        for (int i = threadIdx.x; i < cnt; i += 256) {
            int2 ed = st8[ebase + base + i];
            int dl = st1[ebase + base + i];
            int p = atomicAdd(&gc[lo + dl], 1);
            eo[p] = ed;
        }
    }
}

// ---------------- dense GEMM: cur(bf16) and sum(fp32) = X[n,384] @ W[384,128] ----------------

__global__ void gemm_kernel(const float* __restrict__ X, const float* __restrict__ W, int n,
                            unsigned* __restrict__ curh, float* __restrict__ sum) {
    __shared__ float sx[8 * IN_DIM];
    int base = blockIdx.x * 8;
    for (int i = threadIdx.x; i < 8 * IN_DIM; i += 256) {
        int r = base + i / IN_DIM;
        sx[i] = (r < n) ? X[(size_t)r * IN_DIM + (i % IN_DIM)] : 0.f;
    }
    __syncthreads();
    int col = threadIdx.x & 127;
    int rh  = threadIdx.x >> 7;  // 0 or 1
    float acc[4] = {0.f, 0.f, 0.f, 0.f};
    for (int k = 0; k < IN_DIM; ++k) {
        float wv = W[k * D + col];
#pragma unroll
        for (int j = 0; j < 4; ++j)
            acc[j] += sx[(rh * 4 + j) * IN_DIM + k] * wv;
    }
#pragma unroll
    for (int j = 0; j < 4; ++j) {
        int r = base + rh * 4 + j;
        if (r < n) {
            size_t o = (size_t)r * D + col;
            sum[o] = acc[j];
            ((unsigned short*)curh)[o] = (unsigned short)bf16rn(acc[j]);
        }
    }
}

// ---------------- fused pull SpMM ----------------
// One wave per dst row, 4 quarters x 16 lanes; each quarter owns one edge; lane gathers
// uint4 (16B) of the 256B bf16 source row; unroll x2 -> 2KB of gathers in flight.

__global__ void spmm_fused(const int* __restrict__ rp1, const int2* __restrict__ e1,
                           const int* __restrict__ rp2, const int2* __restrict__ e2,
                           const uint4* __restrict__ x1, const uint4* __restrict__ x2,
                           uint4* __restrict__ y_nxt, float4* __restrict__ sum, int n) {
    int wave = threadIdx.x >> 6;
    int lane = threadIdx.x & 63;
    int q = lane >> 4;
    int l = lane & 15;
    int r = blockIdx.x * 4 + wave;
    if (r >= n) return;

    float acc[8];
#pragma unroll
    for (int k = 0; k < 8; ++k) acc[k] = 0.f;

#pragma unroll
    for (int pass = 0; pass < 2; ++pass) {
        const int* rp = pass ? rp2 : rp1;
        const int2* edges = pass ? e2 : e1;
        const uint4* xv = pass ? x2 : x1;
        int s = rp[r], e = rp[r + 1];
        int i = s;
        for (; i + 8 <= e; i += 8) {
            int2 edA = edges[i + q];
            int2 edB = edges[i + 4 + q];
            uint4 uA = xv[(size_t)edA.x * 16 + l];
            uint4 uB = xv[(size_t)edB.x * 16 + l];
            fma8(acc, __int_as_float(edA.y), uA);
            fma8(acc, __int_as_float(edB.y), uB);
        }
        if (i < e) {
            int idx = i + q;
            bool valid = idx < e;
            int2 ed = edges[valid ? idx : (e - 1)];
            uint4 u = xv[(size_t)ed.x * 16 + l];
            fma8(acc, valid ? __int_as_float(ed.y) : 0.f, u);
            i += 4;
            if (i < e) {
                idx = i + q;
                valid = idx < e;
                int2 ed2 = edges[valid ? idx : (e - 1)];
                uint4 u2 = xv[(size_t)ed2.x * 16 + l];
                fma8(acc, valid ? __int_as_float(ed2.y) : 0.f, u2);
            }
        }
    }

#pragma unroll
    for (int k = 0; k < 8; ++k) {
        acc[k] += __shfl_xor(acc[k], 16);
        acc[k] += __shfl_xor(acc[k], 32);
    }

    if (q == 0) {
        uint4 p;
        p.x = bf16rn(acc[0]) | (bf16rn(acc[1]) << 16);
        p.y = bf16rn(acc[2]) | (bf16rn(acc[3]) << 16);
        p.z = bf16rn(acc[4]) | (bf16rn(acc[5]) << 16);
        p.w = bf16rn(acc[6]) | (bf16rn(acc[7]) << 16);
        y_nxt[(size_t)r * 16 + l] = p;
        float4* sp = sum + (size_t)r * 32 + 2 * l;
        float4 s0 = sp[0], s1 = sp[1];
        s0.x += acc[0]; s0.y += acc[1]; s0.z += acc[2]; s0.w += acc[3];
        s1.x += acc[4]; s1.y += acc[5]; s1.z += acc[6]; s1.w += acc[7];
        sp[0] = s0; sp[1] = s1;
    }
}

// ---------------- normalize ----------------

__global__ void norm_kernel(float* __restrict__ out, int n) {
    int wave = threadIdx.x >> 6;
    int lane = threadIdx.x & 63;
    int r = blockIdx.x * 4 + wave;
    if (r >= n) return;
    float2* p = (float2*)out + (size_t)r * 64 + lane;
    float2 v = *p;
    v.x *= 0.25f;
    v.y *= 0.25f;
    float ss = v.x * v.x + v.y * v.y;
    for (int off = 32; off > 0; off >>= 1) ss += __shfl_down(ss, off);
    ss = __shfl(ss, 0);
    float inv = 1.f / fmaxf(sqrtf(ss), 1e-12f);
    v.x *= inv;
    v.y *= inv;
    *p = v;
}

// ---------------- launch ----------------

extern "C" void kernel_launch(void* const* d_in, const int* in_sizes, int n_in,
                              void* d_out, int out_size, void* d_ws, size_t ws_size,
                              hipStream_t stream) {
    const float* user_feat = (const float*)d_in[0];
    const float* biz_feat  = (const float*)d_in[1];
    const float* W_user    = (const float*)d_in[2];
    const float* W_biz     = (const float*)d_in[3];
    const int*   ub_u      = (const int*)d_in[4];
    const int*   ub_b      = (const int*)d_in[5];
    const float* val_ub    = (const float*)d_in[6];
    const float* val_bu    = (const float*)d_in[7];
    const int*   uu_src    = (const int*)d_in[8];
    const int*   uu_dst    = (const int*)d_in[9];
    const float* uu_val    = (const float*)d_in[10];
    const int*   bb_src    = (const int*)d_in[11];
    const int*   bb_dst    = (const int*)d_in[12];
    const float* bb_val    = (const float*)d_in[13];

    float* out   = (float*)d_out;
    float* u_sum = out;
    float* b_sum = out + (size_t)N_U * D;

    char* ws = (char*)d_ws;
    size_t off = 0;
    auto alloc = [&](size_t bytes) -> void* {
        void* p = ws + off;
        off += (bytes + 255) & ~(size_t)255;
        return p;
    };
    unsigned* u_curh = (unsigned*)alloc((size_t)N_U * 64 * 4);   // bf16 [N_U,128]
    unsigned* b_curh = (unsigned*)alloc((size_t)N_B * 64 * 4);
    int2* e_bu = (int2*)alloc((size_t)E_UB * 8);
    int2* e_uu = (int2*)alloc((size_t)E_UU * 8);
    int2* e_ub = (int2*)alloc((size_t)E_UB * 8);
    int2* e_bb = (int2*)alloc((size_t)E_BB * 8);
    int*  cnt  = (int*)alloc((size_t)(2 * N_U + 2 * N_B) * 4);
    int*  rp_bu = (int*)alloc((N_U + 1) * 4);
    int*  rp_uu = (int*)alloc((N_U + 1) * 4);
    int*  rp_ub = (int*)alloc((N_B + 1) * 4);
    int*  rp_bb = (int*)alloc((N_B + 1) * 4);
    int*  bcur  = (int*)alloc(NB_TOT * 4);
    // staging region; u_nxth/b_nxth alias its head (used only after phaseB completes)
    int2* st8 = (int2*)alloc((size_t)E_TOT * 8);
    unsigned char* st1 = (unsigned char*)alloc(E_TOT);
    unsigned* u_nxth = (unsigned*)st8;
    unsigned* b_nxth = (unsigned*)((char*)st8 + (size_t)N_U * 64 * 4);

    int* cnt_bu = cnt;
    int* cnt_uu = cnt + N_U;
    int* cnt_ub = cnt + 2 * N_U;
    int* cnt_bb = cnt + 2 * N_U + N_B;

    hipMemsetAsync(cnt, 0, sizeof(int) * (2 * N_U + 2 * N_B), stream);

    count_all<<<4096, 256, 0, stream>>>(ub_u, uu_dst, ub_b, bb_dst, cnt);
    scan4<<<4, 1024, 0, stream>>>(cnt_bu, rp_bu, cnt_uu, rp_uu, cnt_ub, rp_ub, cnt_bb, rp_bb);
    binit<<<16, 256, 0, stream>>>(rp_bu, rp_uu, rp_ub, rp_bb, bcur);
    phaseA<<<4096, 256, 0, stream>>>(ub_u,   ub_b,   val_bu,
                                     uu_dst, uu_src, uu_val,
                                     ub_b,   ub_u,   val_ub,
                                     bb_dst, bb_src, bb_val,
                                     bcur, st8, st1);
    phaseB<<<NB_TOT, 256, 0, stream>>>(rp_bu, rp_uu, rp_ub, rp_bb,
                                       e_bu, e_uu, e_ub, e_bb,
                                       cnt_bu, cnt_uu, cnt_ub, cnt_bb,
                                       st8, st1);

    gemm_kernel<<<(N_U + 7) / 8, 256, 0, stream>>>(user_feat, W_user, N_U, u_curh, u_sum);
    gemm_kernel<<<(N_B + 7) / 8, 256, 0, stream>>>(biz_feat,  W_biz,  N_B, b_curh, b_sum);

    for (int l = 0; l < 3; ++l) {
        spmm_fused<<<(N_U + 3) / 4, 256, 0, stream>>>(rp_bu, e_bu, rp_uu, e_uu,
                                                      (const uint4*)b_curh, (const uint4*)u_curh,
                                                      (uint4*)u_nxth, (float4*)u_sum, N_U);
        spmm_fused<<<(N_B + 3) / 4, 256, 0, stream>>>(rp_ub, e_ub, rp_bb, e_bb,
                                                      (const uint4*)u_curh, (const uint4*)b_curh,
                                                      (uint4*)b_nxth, (float4*)b_sum, N_B);
        unsigned* t;
        t = u_curh; u_curh = u_nxth; u_nxth = t;
        t = b_curh; b_curh = b_nxth; b_nxth = t;
    }

    norm_kernel<<<(N_U + 3) / 4, 256, 0, stream>>>(u_sum, N_U);
    norm_kernel<<<(N_B + 3) / 4, 256, 0, stream>>>(b_sum, N_B);
}